// Round 1
// baseline (458.100 us; speedup 1.0000x reference)
//
#include <hip/hip_runtime.h>
#include <hip/hip_bf16.h>
#include <cstdint>
#include <cstddef>

// Problem constants
#define BB    4
#define NN    4096
#define DIM   1024
#define HEADS 16
#define DH    64
#define DIN   1024        // HEADS*DH
#define NQO   3072        // 3*DIN
#define MTOT  (BB*NN)     // 16384
#define KDIM  1024
#define EPS_F 1e-12f

using bf16 = __hip_bfloat16;
typedef __attribute__((ext_vector_type(8))) short bf16x8;
typedef __attribute__((ext_vector_type(4))) float f32x4;

// ---------------------------------------------------------------- helpers
__device__ __forceinline__ void gload_lds16(const void* g, void* l) {
    __builtin_amdgcn_global_load_lds(
        (const __attribute__((address_space(1))) void*)g,
        (__attribute__((address_space(3))) void*)l,
        16, 0, 0);
}

__device__ __forceinline__ ushort bf16_bits(float x) {
    union { bf16 h; ushort u; } c;
    c.h = __float2bfloat16(x);
    return c.u;
}

// ---------------------------------------------------------------- kernel 1: RMSNorm -> bf16
// xn[row][c] = x[row][c] * (sqrt(DIM)/max(||x_row||,eps)) * gamma[c]
__global__ __launch_bounds__(256) void k_rmsnorm(const float* __restrict__ x,
                                                 const float* __restrict__ gamma,
                                                 bf16* __restrict__ xn) {
    int row = blockIdx.x;
    int t = threadIdx.x;                 // 256 threads, 4 f32 each = 1024
    const float4* xr = (const float4*)(x + (size_t)row * DIM);
    float4 v = xr[t];
    float ss = v.x * v.x + v.y * v.y + v.z * v.z + v.w * v.w;
#pragma unroll
    for (int off = 32; off; off >>= 1) ss += __shfl_down(ss, off, 64);
    __shared__ float red[4];
    int lane = t & 63, w = t >> 6;
    if (lane == 0) red[w] = ss;
    __syncthreads();
    float tot = red[0] + red[1] + red[2] + red[3];
    float scale = 32.0f / fmaxf(sqrtf(tot), EPS_F);   // sqrt(1024)=32
    float4 g = ((const float4*)gamma)[t];
    union { ushort4 u4; ushort us[4]; } o;
    o.us[0] = bf16_bits(v.x * scale * g.x);
    o.us[1] = bf16_bits(v.y * scale * g.y);
    o.us[2] = bf16_bits(v.z * scale * g.z);
    o.us[3] = bf16_bits(v.w * scale * g.w);
    ((ushort4*)(xn + (size_t)row * DIM))[t] = o.u4;
}

// ---------------------------------------------------------------- kernel 2: f32 -> bf16 cast
__global__ __launch_bounds__(256) void k_cast_bf16(const float* __restrict__ s,
                                                   bf16* __restrict__ d, int n4) {
    int i = blockIdx.x * blockDim.x + threadIdx.x;
    if (i >= n4) return;
    float4 v = ((const float4*)s)[i];
    union { ushort4 u4; ushort us[4]; } o;
    o.us[0] = bf16_bits(v.x); o.us[1] = bf16_bits(v.y);
    o.us[2] = bf16_bits(v.z); o.us[3] = bf16_bits(v.w);
    ((ushort4*)d)[i] = o.u4;
}

// ---------------------------------------------------------------- kernel 3: QKV GEMM (m97 structure)
// C[m,o] = sum_k A[m,k]*W[o,k]; A: xn (16384x1024 bf16), W: w_qkv (3072x1024 bf16)
// Output scattered transposed into qkv f32 laid out (3,b,h,dh,n): row-contig in n.
__global__ __launch_bounds__(256, 2) void k_gemm_qkv(const bf16* __restrict__ A,
                                                     const bf16* __restrict__ W,
                                                     float* __restrict__ qkv) {
    __shared__ short As[128 * 32];
    __shared__ short Bs[128 * 32];
    const int tm = blockIdx.x * 128;
    const int tn = blockIdx.y * 128;
    const int t = threadIdx.x, lane = t & 63, w = t >> 6;
    const int wr = w >> 1, wc = w & 1;

    f32x4 acc[4][4] = {};

    // staging: chunk c = w*2 + i covers rows [c*16, c*16+16), lane l writes bytes c*1024+l*16
    const int ca = w * 2;
    const int rowS = ca * 16 + (lane >> 2);
    const int kofs = (lane & 3) * 8;
    const bf16* Ab = A + (size_t)(tm + rowS) * KDIM + kofs;
    const bf16* Bb = W + (size_t)(tn + rowS) * KDIM + kofs;
    short* AsD0 = As + ca * 512;
    short* AsD1 = As + (ca + 1) * 512;
    short* BsD0 = Bs + ca * 512;
    short* BsD1 = Bs + (ca + 1) * 512;

    const int rbA = wr * 64 + (lane & 15);
    const int rbB = wc * 64 + (lane & 15);
    const int kh = (lane >> 4) * 8;

    for (int kk = 0; kk < KDIM; kk += 32) {
        __syncthreads();
        gload_lds16(Ab + kk, AsD0);
        gload_lds16(Ab + kk + 16 * KDIM, AsD1);
        gload_lds16(Bb + kk, BsD0);
        gload_lds16(Bb + kk + 16 * KDIM, BsD1);
        __syncthreads();
        bf16x8 af[4], bfr[4];
#pragma unroll
        for (int i = 0; i < 4; ++i) {
            af[i]  = *(const bf16x8*)(As + (rbA + i * 16) * 32 + kh);
            bfr[i] = *(const bf16x8*)(Bs + (rbB + i * 16) * 32 + kh);
        }
#pragma unroll
        for (int i = 0; i < 4; ++i)
#pragma unroll
            for (int j = 0; j < 4; ++j)
                acc[i][j] = __builtin_amdgcn_mfma_f32_16x16x32_bf16(af[i], bfr[j], acc[i][j], 0, 0, 0);
    }

    // epilogue: transposed scatter. C/D frag: col=lane&15, row=(lane>>4)*4+reg
    const int b = tm >> 12;           // 4096 rows per batch, tile never straddles
#pragma unroll
    for (int i = 0; i < 4; ++i) {
        int mg = tm + wr * 64 + i * 16 + (lane >> 4) * 4;
        int nseq = mg & (NN - 1);
#pragma unroll
        for (int j = 0; j < 4; ++j) {
            int o = tn + wc * 64 + j * 16 + (lane & 15);
            size_t off = ((size_t)((o >> 10) * 4 + b) * 1024 + (o & 1023)) * (size_t)NN + nseq;
            *(f32x4*)(qkv + off) = acc[i][j];
        }
    }
}

// ---------------------------------------------------------------- kernel 4: per-row inv norms (q,k)
// rows 0..4095 = q rows, 4096..8191 = k rows; each row 4096 f32 contiguous
__global__ __launch_bounds__(256) void k_rownorm(const float* __restrict__ qkv,
                                                 float* __restrict__ inv) {
    int row = blockIdx.x;
    const float4* p = (const float4*)(qkv + (size_t)row * NN);
    int t = threadIdx.x;
    float ss = 0.f;
#pragma unroll
    for (int i = 0; i < 4; ++i) {
        float4 v = p[t + i * 256];
        ss += v.x * v.x + v.y * v.y + v.z * v.z + v.w * v.w;
    }
#pragma unroll
    for (int off = 32; off; off >>= 1) ss += __shfl_down(ss, off, 64);
    __shared__ float red[4];
    int lane = t & 63, w = t >> 6;
    if (lane == 0) red[w] = ss;
    __syncthreads();
    if (t == 0) {
        float tot = red[0] + red[1] + red[2] + red[3];
        inv[row] = 1.0f / fmaxf(sqrtf(tot), EPS_F);
    }
}

// ---------------------------------------------------------------- kernel 5: sim partials
// part[bh][chunk][d][e] = sum_{n in chunk} q[bh,d,n]*k[bh,e,n]  (raw, unnormalized)
__global__ __launch_bounds__(256) void k_sim(const float* __restrict__ qkv,
                                             float* __restrict__ part) {
    int chunk = blockIdx.x;   // 0..7 (512 n each)
    int bh = blockIdx.y;      // 0..63
    __shared__ float Qs[64 * 68];
    __shared__ float Ks[64 * 68];
    const float* qb = qkv + (size_t)(bh * 64) * NN;
    const float* kb = qkv + (size_t)(4096 + bh * 64) * NN;
    int t = threadIdx.x, lane = t & 63, w = t >> 6;
    float acc[4][4] = {};
    const int d0 = w * 16 + (lane >> 4) * 4;   // 4 consecutive d rows
    const int e0 = lane & 15;                  // e rows e0 + 16*ee

    const int sr = t >> 2, sj = (t & 3) * 16;  // staging: row sr, 16 floats at sj
    for (int nt = 0; nt < 8; ++nt) {
        int nbase = chunk * 512 + nt * 64;
        __syncthreads();
        const float4* qsrc = (const float4*)(qb + (size_t)sr * NN + nbase + sj);
        const float4* ksrc = (const float4*)(kb + (size_t)sr * NN + nbase + sj);
        float4* qd = (float4*)(Qs + sr * 68 + sj);
        float4* kd = (float4*)(Ks + sr * 68 + sj);
#pragma unroll
        for (int u = 0; u < 4; ++u) { qd[u] = qsrc[u]; kd[u] = ksrc[u]; }
        __syncthreads();
#pragma unroll 2
        for (int j = 0; j < 64; j += 4) {
            float4 qv[4], kv[4];
#pragma unroll
            for (int dd = 0; dd < 4; ++dd) qv[dd] = *(const float4*)(Qs + (d0 + dd) * 68 + j);
#pragma unroll
            for (int ee = 0; ee < 4; ++ee) kv[ee] = *(const float4*)(Ks + (e0 + ee * 16) * 68 + j);
#pragma unroll
            for (int dd = 0; dd < 4; ++dd)
#pragma unroll
                for (int ee = 0; ee < 4; ++ee)
                    acc[dd][ee] += qv[dd].x * kv[ee].x + qv[dd].y * kv[ee].y +
                                   qv[dd].z * kv[ee].z + qv[dd].w * kv[ee].w;
        }
    }
    float* pb = part + ((size_t)(bh * 8 + chunk) * 64) * 64;
#pragma unroll
    for (int dd = 0; dd < 4; ++dd)
#pragma unroll
        for (int ee = 0; ee < 4; ++ee)
            pb[(d0 + dd) * 64 + (e0 + ee * 16)] = acc[dd][ee];
}

// ---------------------------------------------------------------- kernel 6: scale + softmax
// attnT[bh][e][d] = softmax_e( 8*exp(T[h])*invq[d]*invk[e]*sim_raw[d][e] )  (stored transposed)
__global__ __launch_bounds__(64) void k_softmax(const float* __restrict__ part,
                                                const float* __restrict__ inv,
                                                const float* __restrict__ temp,
                                                float* __restrict__ attnT) {
    int bh = blockIdx.x;
    int h = bh & (HEADS - 1);
    int e = threadIdx.x;    // 64 lanes
    float expT = __expf(temp[h]);
    float ike = inv[4096 + bh * 64 + e];
    for (int d = 0; d < 64; ++d) {
        float s = 0.f;
#pragma unroll
        for (int c = 0; c < 8; ++c)
            s += part[((size_t)(bh * 8 + c) * 64 + d) * 64 + e];
        float logit = s * 8.0f * expT * inv[bh * 64 + d] * ike;
        float m = logit;
#pragma unroll
        for (int off = 32; off; off >>= 1) m = fmaxf(m, __shfl_xor(m, off, 64));
        float p = __expf(logit - m);
        float sum = p;
#pragma unroll
        for (int off = 32; off; off >>= 1) sum += __shfl_xor(sum, off, 64);
        attnT[(size_t)bh * 4096 + e * 64 + d] = p / sum;
    }
}

// ---------------------------------------------------------------- kernel 7: attn @ v -> A2 bf16 (b,n,h*d)
// out[d,n] = sum_e attn[d,e]*v[e,n]; A2[b][n][h*64+d] = bf16(out)
__global__ __launch_bounds__(256, 2) void k_attnv(const float* __restrict__ qkv,
                                                  const float* __restrict__ attnT,
                                                  bf16* __restrict__ A2) {
    int nchunk = blockIdx.x;  // 0..3 (1024 n each)
    int bh = blockIdx.y;      // 0..63
    int dz = blockIdx.z;      // 0..1 (d half)
    int t = threadIdx.x;
    int n = nchunk * 1024 + t * 4;
    const float* vb = qkv + (size_t)(8192 + bh * 64) * NN;
    const float* at = attnT + (size_t)bh * 4096 + dz * 32;   // [e][d-half]
    float acc[32][4];
#pragma unroll
    for (int d = 0; d < 32; ++d)
#pragma unroll
        for (int r = 0; r < 4; ++r) acc[d][r] = 0.f;

    for (int e = 0; e < 64; ++e) {
        float4 vv = *(const float4*)(vb + (size_t)e * NN + n);
        const float* arow = at + e * 64;     // uniform -> s_loads
#pragma unroll
        for (int d = 0; d < 32; ++d) {
            float a = arow[d];
            acc[d][0] = fmaf(a, vv.x, acc[d][0]);
            acc[d][1] = fmaf(a, vv.y, acc[d][1]);
            acc[d][2] = fmaf(a, vv.z, acc[d][2]);
            acc[d][3] = fmaf(a, vv.w, acc[d][3]);
        }
    }
    int b = bh >> 4, h = bh & 15;
#pragma unroll
    for (int r = 0; r < 4; ++r) {
        bf16* dst = A2 + (size_t)(b * NN + n + r) * DIN + h * 64 + dz * 32;
        alignas(16) ushort tmp[32];
#pragma unroll
        for (int d = 0; d < 32; ++d) tmp[d] = bf16_bits(acc[d][r]);
        uint4* d4 = (uint4*)dst;
        const uint4* s4 = (const uint4*)tmp;
        d4[0] = s4[0]; d4[1] = s4[1]; d4[2] = s4[2]; d4[3] = s4[3];
    }
}

// ---------------------------------------------------------------- kernel 8: output GEMM
// out[m,o] = sum_k A2[m,k]*Wout[o,k]; row-major f32 store
__global__ __launch_bounds__(256, 2) void k_gemm_out(const bf16* __restrict__ A,
                                                     const bf16* __restrict__ W,
                                                     float* __restrict__ out) {
    __shared__ short As[128 * 32];
    __shared__ short Bs[128 * 32];
    const int tm = blockIdx.x * 128;
    const int tn = blockIdx.y * 128;
    const int t = threadIdx.x, lane = t & 63, w = t >> 6;
    const int wr = w >> 1, wc = w & 1;

    f32x4 acc[4][4] = {};

    const int ca = w * 2;
    const int rowS = ca * 16 + (lane >> 2);
    const int kofs = (lane & 3) * 8;
    const bf16* Ab = A + (size_t)(tm + rowS) * KDIM + kofs;
    const bf16* Bb = W + (size_t)(tn + rowS) * KDIM + kofs;
    short* AsD0 = As + ca * 512;
    short* AsD1 = As + (ca + 1) * 512;
    short* BsD0 = Bs + ca * 512;
    short* BsD1 = Bs + (ca + 1) * 512;

    const int rbA = wr * 64 + (lane & 15);
    const int rbB = wc * 64 + (lane & 15);
    const int kh = (lane >> 4) * 8;

    for (int kk = 0; kk < KDIM; kk += 32) {
        __syncthreads();
        gload_lds16(Ab + kk, AsD0);
        gload_lds16(Ab + kk + 16 * KDIM, AsD1);
        gload_lds16(Bb + kk, BsD0);
        gload_lds16(Bb + kk + 16 * KDIM, BsD1);
        __syncthreads();
        bf16x8 af[4], bfr[4];
#pragma unroll
        for (int i = 0; i < 4; ++i) {
            af[i]  = *(const bf16x8*)(As + (rbA + i * 16) * 32 + kh);
            bfr[i] = *(const bf16x8*)(Bs + (rbB + i * 16) * 32 + kh);
        }
#pragma unroll
        for (int i = 0; i < 4; ++i)
#pragma unroll
            for (int j = 0; j < 4; ++j)
                acc[i][j] = __builtin_amdgcn_mfma_f32_16x16x32_bf16(af[i], bfr[j], acc[i][j], 0, 0, 0);
    }

#pragma unroll
    for (int i = 0; i < 4; ++i) {
        int mg = tm + wr * 64 + i * 16 + (lane >> 4) * 4;
#pragma unroll
        for (int j = 0; j < 4; ++j) {
            int o = tn + wc * 64 + j * 16 + (lane & 15);
#pragma unroll
            for (int r = 0; r < 4; ++r)
                out[(size_t)(mg + r) * DIN + o] = acc[i][j][r];
        }
    }
}

// ---------------------------------------------------------------- launch
extern "C" void kernel_launch(void* const* d_in, const int* in_sizes, int n_in,
                              void* d_out, int out_size, void* d_ws, size_t ws_size,
                              hipStream_t stream) {
    const float* x      = (const float*)d_in[0];
    const float* gamma  = (const float*)d_in[1];
    const float* w_qkv  = (const float*)d_in[2];
    const float* temp   = (const float*)d_in[3];
    const float* w_out  = (const float*)d_in[4];
    float* out = (float*)d_out;

    char* ws = (char*)d_ws;
    // workspace layout (needs ~253 MB)
    float* qkv   = (float*)ws;                                    // 3*4096*4096*4 = 201326592
    bf16*  xn    = (bf16*)(ws + 201326592);                       // 16384*1024*2  =  33554432
    bf16*  wq_bf = (bf16*)(ws + 201326592 + 33554432);            //  3072*1024*2  =   6291456
    bf16*  wo_bf = (bf16*)(ws + 201326592 + 33554432 + 6291456);  //  1024*1024*2  =   2097152
    float* inv   = (float*)(ws + 201326592 + 33554432 + 6291456 + 2097152);            // 32768
    float* part  = (float*)(ws + 201326592 + 33554432 + 6291456 + 2097152 + 32768);    // 8388608
    float* attnT = (float*)(ws + 201326592 + 33554432 + 6291456 + 2097152 + 32768 + 8388608); // 1048576

    k_rmsnorm<<<MTOT, 256, 0, stream>>>(x, gamma, xn);
    k_cast_bf16<<<(NQO * KDIM / 4 + 255) / 256, 256, 0, stream>>>(w_qkv, wq_bf, NQO * KDIM / 4);
    k_cast_bf16<<<(DIN * KDIM / 4 + 255) / 256, 256, 0, stream>>>(w_out, wo_bf, DIN * KDIM / 4);
    k_gemm_qkv<<<dim3(MTOT / 128, NQO / 128), 256, 0, stream>>>(xn, wq_bf, qkv);
    k_rownorm<<<8192, 256, 0, stream>>>(qkv, inv);
    k_sim<<<dim3(8, 64), 256, 0, stream>>>(qkv, part);
    k_softmax<<<64, 64, 0, stream>>>(part, inv, temp, attnT);
    bf16* A2 = xn;  // xn is dead after GEMM1; reuse as attention-output buffer
    k_attnv<<<dim3(4, 64, 2), 256, 0, stream>>>(qkv, attnT, A2);
    k_gemm_out<<<dim3(MTOT / 128, DIN / 128), 256, 0, stream>>>(A2, wo_bf, out);
}

// Round 3
// 388.153 us; speedup vs baseline: 1.1802x; 1.1802x over previous
//
#include <hip/hip_runtime.h>
#include <hip/hip_bf16.h>
#include <cstdint>
#include <cstddef>

// Problem constants
#define BB    4
#define NN    4096
#define DIM   1024
#define HEADS 16
#define DH    64
#define DIN   1024        // HEADS*DH
#define NQO   3072        // 3*DIN
#define MTOT  (BB*NN)     // 16384
#define KDIM  1024
#define EPS_F 1e-12f

using bf16 = __hip_bfloat16;
typedef __attribute__((ext_vector_type(8))) short bf16x8;
typedef __attribute__((ext_vector_type(4))) float f32x4;

// ---------------------------------------------------------------- helpers
__device__ __forceinline__ void gload_lds16(const void* g, void* l) {
    __builtin_amdgcn_global_load_lds(
        (const __attribute__((address_space(1))) void*)g,
        (__attribute__((address_space(3))) void*)l,
        16, 0, 0);
}

__device__ __forceinline__ ushort bf16_bits(float x) {
    union { bf16 h; ushort u; } c;
    c.h = __float2bfloat16(x);
    return c.u;
}

__device__ __forceinline__ float b2f(ushort u) {
    union { unsigned u32; float f; } c;
    c.u32 = ((unsigned)u) << 16;
    return c.f;
}

// ---------------------------------------------------------------- kernel 1: RMSNorm -> bf16
__global__ __launch_bounds__(256) void k_rmsnorm(const float* __restrict__ x,
                                                 const float* __restrict__ gamma,
                                                 bf16* __restrict__ xn) {
    int row = blockIdx.x;
    int t = threadIdx.x;                 // 256 threads, 4 f32 each = 1024
    const float4* xr = (const float4*)(x + (size_t)row * DIM);
    float4 v = xr[t];
    float ss = v.x * v.x + v.y * v.y + v.z * v.z + v.w * v.w;
#pragma unroll
    for (int off = 32; off; off >>= 1) ss += __shfl_down(ss, off, 64);
    __shared__ float red[4];
    int lane = t & 63, w = t >> 6;
    if (lane == 0) red[w] = ss;
    __syncthreads();
    float tot = red[0] + red[1] + red[2] + red[3];
    float scale = 32.0f / fmaxf(sqrtf(tot), EPS_F);   // sqrt(1024)=32
    float4 g = ((const float4*)gamma)[t];
    union { ushort4 u4; ushort us[4]; } o;
    o.us[0] = bf16_bits(v.x * scale * g.x);
    o.us[1] = bf16_bits(v.y * scale * g.y);
    o.us[2] = bf16_bits(v.z * scale * g.z);
    o.us[3] = bf16_bits(v.w * scale * g.w);
    ((ushort4*)(xn + (size_t)row * DIM))[t] = o.u4;
}

// ---------------------------------------------------------------- kernel 2: f32 -> bf16 cast
__global__ __launch_bounds__(256) void k_cast_bf16(const float* __restrict__ s,
                                                   bf16* __restrict__ d, int n4) {
    int i = blockIdx.x * blockDim.x + threadIdx.x;
    if (i >= n4) return;
    float4 v = ((const float4*)s)[i];
    union { ushort4 u4; ushort us[4]; } o;
    o.us[0] = bf16_bits(v.x); o.us[1] = bf16_bits(v.y);
    o.us[2] = bf16_bits(v.z); o.us[3] = bf16_bits(v.w);
    ((ushort4*)d)[i] = o.u4;
}

// ---------------------------------------------------------------- kernel 3: QKV GEMM (m97 structure)
// C[m,o] = sum_k A[m,k]*W[o,k]; output scattered transposed as bf16 into (3,b,h,dh,n).
// grid: (NQO/128, MTOT/128) -> consecutive blocks share the A panel (L2/L3 reuse)
__global__ __launch_bounds__(256, 2) void k_gemm_qkv(const bf16* __restrict__ A,
                                                     const bf16* __restrict__ W,
                                                     bf16* __restrict__ qkv) {
    __shared__ short As[128 * 32];
    __shared__ short Bs[128 * 32];
    const int tm = blockIdx.y * 128;
    const int tn = blockIdx.x * 128;
    const int t = threadIdx.x, lane = t & 63, w = t >> 6;
    const int wr = w >> 1, wc = w & 1;

    f32x4 acc[4][4] = {};

    const int ca = w * 2;
    const int rowS = ca * 16 + (lane >> 2);
    const int kofs = (lane & 3) * 8;
    const bf16* Ab = A + (size_t)(tm + rowS) * KDIM + kofs;
    const bf16* Bb = W + (size_t)(tn + rowS) * KDIM + kofs;
    short* AsD0 = As + ca * 512;
    short* AsD1 = As + (ca + 1) * 512;
    short* BsD0 = Bs + ca * 512;
    short* BsD1 = Bs + (ca + 1) * 512;

    const int rbA = wr * 64 + (lane & 15);
    const int rbB = wc * 64 + (lane & 15);
    const int kh = (lane >> 4) * 8;

    for (int kk = 0; kk < KDIM; kk += 32) {
        __syncthreads();
        gload_lds16(Ab + kk, AsD0);
        gload_lds16(Ab + kk + 16 * KDIM, AsD1);
        gload_lds16(Bb + kk, BsD0);
        gload_lds16(Bb + kk + 16 * KDIM, BsD1);
        __syncthreads();
        bf16x8 af[4], bfr[4];
#pragma unroll
        for (int i = 0; i < 4; ++i) {
            af[i]  = *(const bf16x8*)(As + (rbA + i * 16) * 32 + kh);
            bfr[i] = *(const bf16x8*)(Bs + (rbB + i * 16) * 32 + kh);
        }
#pragma unroll
        for (int i = 0; i < 4; ++i)
#pragma unroll
            for (int j = 0; j < 4; ++j)
                acc[i][j] = __builtin_amdgcn_mfma_f32_16x16x32_bf16(af[i], bfr[j], acc[i][j], 0, 0, 0);
    }

    // epilogue: transposed bf16 scatter. C/D frag: col=lane&15, row=(lane>>4)*4+reg
    const int b = tm >> 12;           // 4096 rows per batch, tile never straddles
#pragma unroll
    for (int i = 0; i < 4; ++i) {
        int mg = tm + wr * 64 + i * 16 + (lane >> 4) * 4;
        int nseq = mg & (NN - 1);
#pragma unroll
        for (int j = 0; j < 4; ++j) {
            int o = tn + wc * 64 + j * 16 + (lane & 15);
            size_t row = (size_t)((o >> 10) * 4 + b) * 1024 + (o & 1023);
            union { ushort4 u4; ushort us[4]; } pk;
#pragma unroll
            for (int r = 0; r < 4; ++r) pk.us[r] = bf16_bits(acc[i][j][r]);
            *(ushort4*)(qkv + row * NN + nseq) = pk.u4;
        }
    }
}

// ---------------------------------------------------------------- kernel 4: per-row inv norms (q,k) from bf16
__global__ __launch_bounds__(256) void k_rownorm(const bf16* __restrict__ qkv,
                                                 float* __restrict__ inv) {
    int row = blockIdx.x;
    const short* p = (const short*)(qkv + (size_t)row * NN);
    int t = threadIdx.x;
    bf16x8 a = *(const bf16x8*)(p + t * 16);
    bf16x8 b = *(const bf16x8*)(p + t * 16 + 8);
    float ss = 0.f;
#pragma unroll
    for (int i = 0; i < 8; ++i) {
        float fa = b2f((ushort)a[i]), fb = b2f((ushort)b[i]);
        ss += fa * fa + fb * fb;
    }
#pragma unroll
    for (int off = 32; off; off >>= 1) ss += __shfl_down(ss, off, 64);
    __shared__ float red[4];
    int lane = t & 63, w = t >> 6;
    if (lane == 0) red[w] = ss;
    __syncthreads();
    if (t == 0) {
        float tot = red[0] + red[1] + red[2] + red[3];
        inv[row] = 1.0f / fmaxf(sqrtf(tot), EPS_F);
    }
}

// ---------------------------------------------------------------- kernel 5: sim partials via MFMA
// part[bh][chunk][d][e] = sum_{n in chunk} q[bh,d,n]*k[bh,e,n]  (raw bf16 inputs)
// grid (4, 64), block 256 (4 waves; wave w owns d-rows [w*16, w*16+16))
__global__ __launch_bounds__(256) void k_sim(const bf16* __restrict__ qkv,
                                             float* __restrict__ part) {
    __shared__ short Qs[64 * 32];
    __shared__ short Ks[64 * 32];
    const int chunk = blockIdx.x;   // 0..3, 1024 n each
    const int bh = blockIdx.y;      // 0..63
    const int t = threadIdx.x, lane = t & 63, w = t >> 6;
    const bf16* qb = qkv + (size_t)(bh * 64) * NN;
    const bf16* kb = qkv + (size_t)(4096 + bh * 64) * NN;

    // staging: thread t covers LDS bytes [t*16, t*16+16) = row t>>2, col (t&3)*8
    const size_t gofs = (size_t)(t >> 2) * NN + (t & 3) * 8 + chunk * 1024;
    short* QsD = Qs + w * 512;
    short* KsD = Ks + w * 512;

    const int ra = (w * 16 + (lane & 15)) * 32 + (lane >> 4) * 8;
    const int kh = (lane >> 4) * 8;

    f32x4 acc[4] = {};
    for (int nt = 0; nt < 32; ++nt) {
        __syncthreads();
        gload_lds16(qb + gofs + nt * 32, QsD);
        gload_lds16(kb + gofs + nt * 32, KsD);
        __syncthreads();
        bf16x8 af = *(const bf16x8*)(Qs + ra);
#pragma unroll
        for (int j = 0; j < 4; ++j) {
            bf16x8 bfr = *(const bf16x8*)(Ks + (j * 16 + (lane & 15)) * 32 + kh);
            acc[j] = __builtin_amdgcn_mfma_f32_16x16x32_bf16(af, bfr, acc[j], 0, 0, 0);
        }
    }
    float* pb = part + (size_t)(bh * 4 + chunk) * 4096;
#pragma unroll
    for (int j = 0; j < 4; ++j) {
        int e = j * 16 + (lane & 15);
#pragma unroll
        for (int r = 0; r < 4; ++r) {
            int d = w * 16 + (lane >> 4) * 4 + r;
            pb[d * 64 + e] = acc[j][r];
        }
    }
}

// ---------------------------------------------------------------- kernel 6: finalize + softmax
// attnT[bh][e][d] = softmax_e( 8*exp(T[h])*invq[d]*invk[e]*sim[d][e] )
// grid 64, block 256: wave w handles d-rows w*16..w*16+15, lane = e
__global__ __launch_bounds__(256) void k_softfin(const float* __restrict__ part,
                                                 const float* __restrict__ inv,
                                                 const float* __restrict__ temp,
                                                 float* __restrict__ attnT) {
    int bh = blockIdx.x;
    int t = threadIdx.x, lane = t & 63, w = t >> 6;
    int e = lane;
    float expT = __expf(temp[bh & (HEADS - 1)]);
    float ike = inv[4096 + bh * 64 + e] * 8.0f * expT;
    const float* pb = part + (size_t)bh * 4 * 4096;
#pragma unroll 4
    for (int dd = 0; dd < 16; ++dd) {
        int d = w * 16 + dd;
        float s = pb[d * 64 + e] + pb[4096 + d * 64 + e] +
                  pb[8192 + d * 64 + e] + pb[12288 + d * 64 + e];
        float logit = s * ike * inv[bh * 64 + d];
        float m = logit;
#pragma unroll
        for (int off = 32; off; off >>= 1) m = fmaxf(m, __shfl_xor(m, off, 64));
        float p = __expf(logit - m);
        float sum = p;
#pragma unroll
        for (int off = 32; off; off >>= 1) sum += __shfl_xor(sum, off, 64);
        attnT[(size_t)bh * 4096 + e * 64 + d] = p / sum;
    }
}

// ---------------------------------------------------------------- kernel 7: attn @ v -> A2 bf16 (b,n,h*d)
__global__ __launch_bounds__(256) void k_attnv(const bf16* __restrict__ qkv,
                                               const float* __restrict__ attnT,
                                               bf16* __restrict__ A2) {
    int nchunk = blockIdx.x;  // 0..3 (1024 n each)
    int bh = blockIdx.y;      // 0..63
    int dz = blockIdx.z;      // 0..1 (d half)
    int t = threadIdx.x;
    int n = nchunk * 1024 + t * 4;
    const bf16* vb = qkv + (size_t)(8192 + bh * 64) * NN;
    const float* at = attnT + (size_t)bh * 4096 + dz * 32;   // [e][d-half]
    float acc[32][4];
#pragma unroll
    for (int d = 0; d < 32; ++d)
#pragma unroll
        for (int r = 0; r < 4; ++r) acc[d][r] = 0.f;

    for (int e = 0; e < 64; ++e) {
        ushort4 vraw = *(const ushort4*)((const short*)vb + (size_t)e * NN + n);
        float v0 = b2f(vraw.x), v1 = b2f(vraw.y), v2 = b2f(vraw.z), v3 = b2f(vraw.w);
        const float* arow = at + e * 64;     // uniform -> scalar loads
#pragma unroll
        for (int d = 0; d < 32; ++d) {
            float a = arow[d];
            acc[d][0] = fmaf(a, v0, acc[d][0]);
            acc[d][1] = fmaf(a, v1, acc[d][1]);
            acc[d][2] = fmaf(a, v2, acc[d][2]);
            acc[d][3] = fmaf(a, v3, acc[d][3]);
        }
    }
    int b = bh >> 4, h = bh & 15;
#pragma unroll
    for (int r = 0; r < 4; ++r) {
        bf16* dst = A2 + (size_t)(b * NN + n + r) * DIN + h * 64 + dz * 32;
        alignas(16) ushort tmp[32];
#pragma unroll
        for (int d = 0; d < 32; ++d) tmp[d] = bf16_bits(acc[d][r]);
        uint4* d4 = (uint4*)dst;
        const uint4* s4 = (const uint4*)tmp;
        d4[0] = s4[0]; d4[1] = s4[1]; d4[2] = s4[2]; d4[3] = s4[3];
    }
}

// ---------------------------------------------------------------- kernel 8: output GEMM
// out[m,o] = sum_k A2[m,k]*Wout[o,k]; row-major f32 store
// grid: (DIN/128, MTOT/128) -> consecutive blocks share the A panel
__global__ __launch_bounds__(256, 2) void k_gemm_out(const bf16* __restrict__ A,
                                                     const bf16* __restrict__ W,
                                                     float* __restrict__ out) {
    __shared__ short As[128 * 32];
    __shared__ short Bs[128 * 32];
    const int tm = blockIdx.y * 128;
    const int tn = blockIdx.x * 128;
    const int t = threadIdx.x, lane = t & 63, w = t >> 6;
    const int wr = w >> 1, wc = w & 1;

    f32x4 acc[4][4] = {};

    const int ca = w * 2;
    const int rowS = ca * 16 + (lane >> 2);
    const int kofs = (lane & 3) * 8;
    const bf16* Ab = A + (size_t)(tm + rowS) * KDIM + kofs;
    const bf16* Bb = W + (size_t)(tn + rowS) * KDIM + kofs;
    short* AsD0 = As + ca * 512;
    short* AsD1 = As + (ca + 1) * 512;
    short* BsD0 = Bs + ca * 512;
    short* BsD1 = Bs + (ca + 1) * 512;

    const int rbA = wr * 64 + (lane & 15);
    const int rbB = wc * 64 + (lane & 15);
    const int kh = (lane >> 4) * 8;

    for (int kk = 0; kk < KDIM; kk += 32) {
        __syncthreads();
        gload_lds16(Ab + kk, AsD0);
        gload_lds16(Ab + kk + 16 * KDIM, AsD1);
        gload_lds16(Bb + kk, BsD0);
        gload_lds16(Bb + kk + 16 * KDIM, BsD1);
        __syncthreads();
        bf16x8 af[4], bfr[4];
#pragma unroll
        for (int i = 0; i < 4; ++i) {
            af[i]  = *(const bf16x8*)(As + (rbA + i * 16) * 32 + kh);
            bfr[i] = *(const bf16x8*)(Bs + (rbB + i * 16) * 32 + kh);
        }
#pragma unroll
        for (int i = 0; i < 4; ++i)
#pragma unroll
            for (int j = 0; j < 4; ++j)
                acc[i][j] = __builtin_amdgcn_mfma_f32_16x16x32_bf16(af[i], bfr[j], acc[i][j], 0, 0, 0);
    }

#pragma unroll
    for (int i = 0; i < 4; ++i) {
        int mg = tm + wr * 64 + i * 16 + (lane >> 4) * 4;
#pragma unroll
        for (int j = 0; j < 4; ++j) {
            int o = tn + wc * 64 + j * 16 + (lane & 15);
#pragma unroll
            for (int r = 0; r < 4; ++r)
                out[(size_t)(mg + r) * DIN + o] = acc[i][j][r];
        }
    }
}

// ---------------------------------------------------------------- launch
extern "C" void kernel_launch(void* const* d_in, const int* in_sizes, int n_in,
                              void* d_out, int out_size, void* d_ws, size_t ws_size,
                              hipStream_t stream) {
    const float* x      = (const float*)d_in[0];
    const float* gamma  = (const float*)d_in[1];
    const float* w_qkv  = (const float*)d_in[2];
    const float* temp   = (const float*)d_in[3];
    const float* w_out  = (const float*)d_in[4];
    float* out = (float*)d_out;

    char* ws = (char*)d_ws;
    // workspace layout (~148 MB)
    bf16*  qkv   = (bf16*)ws;                                  // 3*4096*4096*2 = 100663296
    bf16*  xn    = (bf16*)(ws + 100663296);                    // 16384*1024*2  =  33554432
    bf16*  wq_bf = (bf16*)(ws + 134217728);                    //  3072*1024*2  =   6291456
    bf16*  wo_bf = (bf16*)(ws + 140509184);                    //  1024*1024*2  =   2097152
    float* inv   = (float*)(ws + 142606336);                   //  8192*4       =     32768
    float* part  = (float*)(ws + 142639104);                   //  64*4*4096*4  =   4194304
    float* attnT = (float*)(ws + 146833408);                   //  64*4096*4    =   1048576

    k_rmsnorm<<<MTOT, 256, 0, stream>>>(x, gamma, xn);
    k_cast_bf16<<<(NQO * KDIM / 4 + 255) / 256, 256, 0, stream>>>(w_qkv, wq_bf, NQO * KDIM / 4);
    k_cast_bf16<<<(DIN * KDIM / 4 + 255) / 256, 256, 0, stream>>>(w_out, wo_bf, DIN * KDIM / 4);
    k_gemm_qkv<<<dim3(NQO / 128, MTOT / 128), 256, 0, stream>>>(xn, wq_bf, qkv);
    k_rownorm<<<8192, 256, 0, stream>>>(qkv, inv);
    k_sim<<<dim3(4, 64), 256, 0, stream>>>(qkv, part);
    k_softfin<<<64, 256, 0, stream>>>(part, inv, temp, attnT);
    bf16* A2 = xn;  // xn is dead after GEMM1; reuse as attention-output buffer
    k_attnv<<<dim3(4, 64, 2), 256, 0, stream>>>(qkv, attnT, A2);
    k_gemm_out<<<dim3(DIN / 128, MTOT / 128), 256, 0, stream>>>(A2, wo_bf, out);
}

// Round 4
// 350.292 us; speedup vs baseline: 1.3078x; 1.1081x over previous
//
#include <hip/hip_runtime.h>
#include <hip/hip_bf16.h>
#include <cstdint>
#include <cstddef>

// Problem constants
#define BB    4
#define NN    4096
#define DIM   1024
#define HEADS 16
#define DH    64
#define DIN   1024        // HEADS*DH
#define NQO   3072        // 3*DIN
#define MTOT  (BB*NN)     // 16384
#define KDIM  1024
#define EPS_F 1e-12f

using bf16 = __hip_bfloat16;
typedef __attribute__((ext_vector_type(8))) short bf16x8;
typedef __attribute__((ext_vector_type(4))) float f32x4;

// ---------------------------------------------------------------- helpers
__device__ __forceinline__ void gload_lds16(const void* g, void* l) {
    __builtin_amdgcn_global_load_lds(
        (const __attribute__((address_space(1))) void*)g,
        (__attribute__((address_space(3))) void*)l,
        16, 0, 0);
}

__device__ __forceinline__ ushort bf16_bits(float x) {
    union { bf16 h; ushort u; } c;
    c.h = __float2bfloat16(x);
    return c.u;
}

__device__ __forceinline__ float b2f(ushort u) {
    union { unsigned u32; float f; } c;
    c.u32 = ((unsigned)u) << 16;
    return c.f;
}

// ---------------------------------------------------------------- kernel 1: RMSNorm -> bf16
__global__ __launch_bounds__(256) void k_rmsnorm(const float* __restrict__ x,
                                                 const float* __restrict__ gamma,
                                                 bf16* __restrict__ xn) {
    int row = blockIdx.x;
    int t = threadIdx.x;                 // 256 threads, 4 f32 each = 1024
    const float4* xr = (const float4*)(x + (size_t)row * DIM);
    float4 v = xr[t];
    float ss = v.x * v.x + v.y * v.y + v.z * v.z + v.w * v.w;
#pragma unroll
    for (int off = 32; off; off >>= 1) ss += __shfl_down(ss, off, 64);
    __shared__ float red[4];
    int lane = t & 63, w = t >> 6;
    if (lane == 0) red[w] = ss;
    __syncthreads();
    float tot = red[0] + red[1] + red[2] + red[3];
    float scale = 32.0f / fmaxf(sqrtf(tot), EPS_F);   // sqrt(1024)=32
    float4 g = ((const float4*)gamma)[t];
    union { ushort4 u4; ushort us[4]; } o;
    o.us[0] = bf16_bits(v.x * scale * g.x);
    o.us[1] = bf16_bits(v.y * scale * g.y);
    o.us[2] = bf16_bits(v.z * scale * g.z);
    o.us[3] = bf16_bits(v.w * scale * g.w);
    ((ushort4*)(xn + (size_t)row * DIM))[t] = o.u4;
}

// ---------------------------------------------------------------- kernel 2: f32 -> bf16 cast
__global__ __launch_bounds__(256) void k_cast_bf16(const float* __restrict__ s,
                                                   bf16* __restrict__ d, int n4) {
    int i = blockIdx.x * blockDim.x + threadIdx.x;
    if (i >= n4) return;
    float4 v = ((const float4*)s)[i];
    union { ushort4 u4; ushort us[4]; } o;
    o.us[0] = bf16_bits(v.x); o.us[1] = bf16_bits(v.y);
    o.us[2] = bf16_bits(v.z); o.us[3] = bf16_bits(v.w);
    ((ushort4*)d)[i] = o.u4;
}

// ---------------------------------------------------------------- kernel 2b: zero ss buffer
__global__ __launch_bounds__(256) void k_zero(float* __restrict__ p, int n) {
    int i = blockIdx.x * 256 + threadIdx.x;
    if (i < n) p[i] = 0.0f;
}

// ---------------------------------------------------------------- kernel 3: QKV GEMM (m97 structure)
// C[m,o] = sum_k A[m,k]*W[o,k].
// q,k (o<2048): scattered transposed bf16 [(mat*4+b)*1024 + h*64+dh][n]
// v   (o>=2048): stored vT layout [bh*4096 + n][dh]  (dh contiguous)
__global__ __launch_bounds__(256, 2) void k_gemm_qkv(const bf16* __restrict__ A,
                                                     const bf16* __restrict__ W,
                                                     bf16* __restrict__ qkv) {
    __shared__ short As[128 * 32];
    __shared__ short Bs[128 * 32];
    const int tm = blockIdx.y * 128;
    const int tn = blockIdx.x * 128;
    const int t = threadIdx.x, lane = t & 63, w = t >> 6;
    const int wr = w >> 1, wc = w & 1;

    f32x4 acc[4][4] = {};

    const int ca = w * 2;
    const int rowS = ca * 16 + (lane >> 2);
    const int kofs = (lane & 3) * 8;
    const bf16* Ab = A + (size_t)(tm + rowS) * KDIM + kofs;
    const bf16* Bb = W + (size_t)(tn + rowS) * KDIM + kofs;
    short* AsD0 = As + ca * 512;
    short* AsD1 = As + (ca + 1) * 512;
    short* BsD0 = Bs + ca * 512;
    short* BsD1 = Bs + (ca + 1) * 512;

    const int rbA = wr * 64 + (lane & 15);
    const int rbB = wc * 64 + (lane & 15);
    const int kh = (lane >> 4) * 8;

    for (int kk = 0; kk < KDIM; kk += 32) {
        __syncthreads();
        gload_lds16(Ab + kk, AsD0);
        gload_lds16(Ab + kk + 16 * KDIM, AsD1);
        gload_lds16(Bb + kk, BsD0);
        gload_lds16(Bb + kk + 16 * KDIM, BsD1);
        __syncthreads();
        bf16x8 af[4], bfr[4];
#pragma unroll
        for (int i = 0; i < 4; ++i) {
            af[i]  = *(const bf16x8*)(As + (rbA + i * 16) * 32 + kh);
            bfr[i] = *(const bf16x8*)(Bs + (rbB + i * 16) * 32 + kh);
        }
#pragma unroll
        for (int i = 0; i < 4; ++i)
#pragma unroll
            for (int j = 0; j < 4; ++j)
                acc[i][j] = __builtin_amdgcn_mfma_f32_16x16x32_bf16(af[i], bfr[j], acc[i][j], 0, 0, 0);
    }

    // epilogue. C/D frag: col=lane&15, row=(lane>>4)*4+reg
    const int b = tm >> 12;           // 4096 rows per batch, tile never straddles
    if (tn < 2048) {
#pragma unroll
        for (int i = 0; i < 4; ++i) {
            int mg = tm + wr * 64 + i * 16 + ((lane >> 4) << 2);
            int nseq = mg & (NN - 1);
#pragma unroll
            for (int j = 0; j < 4; ++j) {
                int o = tn + wc * 64 + j * 16 + (lane & 15);
                size_t row = (size_t)((o >> 10) * 4 + b) * 1024 + (o & 1023);
                union { ushort4 u4; ushort us[4]; } pk;
#pragma unroll
                for (int r = 0; r < 4; ++r) pk.us[r] = bf16_bits(acc[i][j][r]);
                *(ushort4*)(qkv + row * NN + nseq) = pk.u4;
            }
        }
    } else {
        bf16* vT = qkv + (size_t)8192 * NN;   // v region, layout [bh*4096+n][64]
#pragma unroll
        for (int i = 0; i < 4; ++i) {
            int mg = tm + wr * 64 + i * 16 + ((lane >> 4) << 2);
            int nseq = mg & (NN - 1);
#pragma unroll
            for (int j = 0; j < 4; ++j) {
                int o = tn + wc * 64 + j * 16 + (lane & 15);
                int hd = o & 1023;
                size_t base = ((size_t)(b * 16 + (hd >> 6)) * NN + nseq) * 64 + (hd & 63);
#pragma unroll
                for (int r = 0; r < 4; ++r)
                    vT[base + (size_t)r * 64] = __float2bfloat16(acc[i][j][r]);
            }
        }
    }
}

// ---------------------------------------------------------------- kernel 5: sim partials via MFMA + fused row-norm ss
// part[bh][chunk][d][e] = sum_{n in chunk} q[bh,d,n]*k[bh,e,n]
// ss[row] += sum of squares (q rows 0..4095, k rows 4096..8191), via atomics.
// grid (8, 64), block 256 (4 waves). KBLK=128, 2-phase prefetch.
// K-tile in LDS is XOR-swizzled: lds_byte = row*256 + (col ^ ((row&7)<<4));
// realized with linear gload_lds dest + inverse-swizzled global source.
__global__ __launch_bounds__(256) void k_sim(const bf16* __restrict__ qkv,
                                             float* __restrict__ part,
                                             float* __restrict__ ss) {
    __shared__ short Ks[2][8192];   // 2 x 64 rows x 128 bf16 (16 KB each)
    const int chunk = blockIdx.x;   // 0..7, 512 n each
    const int bh = blockIdx.y;      // 0..63
    const int t = threadIdx.x, lane = t & 63, w = t >> 6;
    const bf16* qb = qkv + (size_t)(bh * 64) * NN;
    const bf16* kb = qkv + (size_t)(4096 + bh * 64) * NN;
    const int n0b = chunk * 512;

#define SIM_STAGE(buf, nt) do {                                              \
    int n0_ = n0b + (nt) * 128;                                              \
    _Pragma("unroll")                                                        \
    for (int cc = 0; cc < 4; ++cc) {                                         \
        int row_ = cc * 16 + (t >> 4);                                       \
        int colb_ = ((t & 15) << 4) ^ ((row_ & 7) << 4);                     \
        gload_lds16(kb + (size_t)row_ * NN + n0_ + (colb_ >> 1),             \
                    &Ks[buf][cc * 2048 + w * 512]);                          \
    }                                                                        \
} while (0)

    f32x4 acc[4] = {};
    float ssq = 0.f, ssk = 0.f;

    SIM_STAGE(0, 0);
    __syncthreads();
    for (int nt = 0; nt < 4; ++nt) {
        if (nt < 3) SIM_STAGE((nt + 1) & 1, nt + 1);
        {
            const int buf = nt & 1;
            const int n0 = n0b + nt * 128;
            bf16x8 af[4];
#pragma unroll
            for (int ks = 0; ks < 4; ++ks) {
                af[ks] = *(const bf16x8*)(qb + (size_t)(w * 16 + (lane & 15)) * NN +
                                          n0 + ks * 32 + ((lane >> 4) << 3));
#pragma unroll
                for (int i = 0; i < 8; ++i) { float f = b2f((ushort)af[ks][i]); ssq += f * f; }
            }
#pragma unroll
            for (int j = 0; j < 4; ++j) {
                int e = j * 16 + (lane & 15);
#pragma unroll
                for (int ks = 0; ks < 4; ++ks) {
                    bf16x8 bfr = *(const bf16x8*)((const char*)&Ks[buf][0] + e * 256 +
                                  ((ks * 64 + ((lane >> 4) << 4)) ^ ((e & 7) << 4)));
                    if (j == w) {
#pragma unroll
                        for (int i = 0; i < 8; ++i) { float f = b2f((ushort)bfr[i]); ssk += f * f; }
                    }
                    acc[j] = __builtin_amdgcn_mfma_f32_16x16x32_bf16(af[ks], bfr, acc[j], 0, 0, 0);
                }
            }
        }
        __syncthreads();
    }
#undef SIM_STAGE

    // row sum-of-squares -> atomics (q row = w*16 + (lane&15); k rows e = w*16 + (lane&15))
    float vq = ssq; vq += __shfl_xor(vq, 16, 64); vq += __shfl_xor(vq, 32, 64);
    if (lane < 16) atomicAdd(&ss[bh * 64 + w * 16 + lane], vq);
    float vk = ssk; vk += __shfl_xor(vk, 16, 64); vk += __shfl_xor(vk, 32, 64);
    if (lane < 16) atomicAdd(&ss[4096 + bh * 64 + w * 16 + lane], vk);

    float* pb = part + (size_t)(bh * 8 + chunk) * 4096;
#pragma unroll
    for (int j = 0; j < 4; ++j) {
        int e = j * 16 + (lane & 15);
#pragma unroll
        for (int r = 0; r < 4; ++r) {
            int d = w * 16 + ((lane >> 4) << 2) + r;
            pb[d * 64 + e] = acc[j][r];
        }
    }
}

// ---------------------------------------------------------------- kernel 6: finalize + softmax -> bf16 attn[d][e]
// grid 64, block 256: wave w handles d-rows w*16..w*16+15, lane = e
__global__ __launch_bounds__(256) void k_softfin(const float* __restrict__ part,
                                                 const float* __restrict__ ss,
                                                 const float* __restrict__ temp,
                                                 bf16* __restrict__ attn) {
    int bh = blockIdx.x;
    int t = threadIdx.x, e = t & 63, w = t >> 6;
    float expT = __expf(temp[bh & (HEADS - 1)]);
    float ike = 8.0f * expT / fmaxf(sqrtf(ss[4096 + bh * 64 + e]), EPS_F);
    const float* pb = part + (size_t)bh * 8 * 4096;
#pragma unroll 2
    for (int dd = 0; dd < 16; ++dd) {
        int d = w * 16 + dd;
        float s = 0.f;
#pragma unroll
        for (int c = 0; c < 8; ++c) s += pb[c * 4096 + d * 64 + e];
        float invq = 1.0f / fmaxf(sqrtf(ss[bh * 64 + d]), EPS_F);
        float logit = s * ike * invq;
        float m = logit;
#pragma unroll
        for (int off = 32; off; off >>= 1) m = fmaxf(m, __shfl_xor(m, off, 64));
        float p = __expf(logit - m);
        float sum = p;
#pragma unroll
        for (int off = 32; off; off >>= 1) sum += __shfl_xor(sum, off, 64);
        attn[(size_t)bh * 4096 + d * 64 + e] = __float2bfloat16(p / sum);
    }
}

// ---------------------------------------------------------------- kernel 7: attn @ v via MFMA (no LDS, no barriers)
// D[n][d] = sum_e vT[n][e] * attn[d][e]; A2[b][n][h*64+d] = bf16(D)
// grid (16, 64), block 256 (4 waves, 64 n-rows each)
__global__ __launch_bounds__(256) void k_attnv(const bf16* __restrict__ qkv,
                                               const bf16* __restrict__ attn,
                                               bf16* __restrict__ A2) {
    const int nc = blockIdx.x;   // 0..15 (256 n each)
    const int bh = blockIdx.y;   // 0..63
    const int t = threadIdx.x, lane = t & 63, w = t >> 6;
    const bf16* vT = qkv + (size_t)8192 * NN + (size_t)bh * NN * 64;
    const bf16* ab = attn + (size_t)bh * 4096;
    const int nbase = nc * 256 + w * 64;

    bf16x8 bfr[4][2];
#pragma unroll
    for (int df = 0; df < 4; ++df)
#pragma unroll
        for (int ks = 0; ks < 2; ++ks)
            bfr[df][ks] = *(const bf16x8*)(ab + (df * 16 + (lane & 15)) * 64 +
                                           ks * 32 + ((lane >> 4) << 3));

    f32x4 acc[4][4] = {};
#pragma unroll
    for (int nf = 0; nf < 4; ++nf) {
#pragma unroll
        for (int ks = 0; ks < 2; ++ks) {
            bf16x8 af = *(const bf16x8*)(vT + (size_t)(nbase + nf * 16 + (lane & 15)) * 64 +
                                         ks * 32 + ((lane >> 4) << 3));
#pragma unroll
            for (int df = 0; df < 4; ++df)
                acc[nf][df] = __builtin_amdgcn_mfma_f32_16x16x32_bf16(af, bfr[df][ks], acc[nf][df], 0, 0, 0);
        }
    }
    const int b = bh >> 4, h = bh & 15;
#pragma unroll
    for (int nf = 0; nf < 4; ++nf)
#pragma unroll
        for (int df = 0; df < 4; ++df)
#pragma unroll
            for (int r = 0; r < 4; ++r) {
                int n = nbase + nf * 16 + ((lane >> 4) << 2) + r;
                int d = df * 16 + (lane & 15);
                A2[(size_t)(b * NN + n) * DIN + h * 64 + d] = __float2bfloat16(acc[nf][df][r]);
            }
}

// ---------------------------------------------------------------- kernel 8: output GEMM
// out[m,o] = sum_k A2[m,k]*Wout[o,k]; row-major f32 store
// grid: (DIN/128, MTOT/128) -> consecutive blocks share the A panel
__global__ __launch_bounds__(256, 2) void k_gemm_out(const bf16* __restrict__ A,
                                                     const bf16* __restrict__ W,
                                                     float* __restrict__ out) {
    __shared__ short As[128 * 32];
    __shared__ short Bs[128 * 32];
    const int tm = blockIdx.y * 128;
    const int tn = blockIdx.x * 128;
    const int t = threadIdx.x, lane = t & 63, w = t >> 6;
    const int wr = w >> 1, wc = w & 1;

    f32x4 acc[4][4] = {};

    const int ca = w * 2;
    const int rowS = ca * 16 + (lane >> 2);
    const int kofs = (lane & 3) * 8;
    const bf16* Ab = A + (size_t)(tm + rowS) * KDIM + kofs;
    const bf16* Bb = W + (size_t)(tn + rowS) * KDIM + kofs;
    short* AsD0 = As + ca * 512;
    short* AsD1 = As + (ca + 1) * 512;
    short* BsD0 = Bs + ca * 512;
    short* BsD1 = Bs + (ca + 1) * 512;

    const int rbA = wr * 64 + (lane & 15);
    const int rbB = wc * 64 + (lane & 15);
    const int kh = (lane >> 4) * 8;

    for (int kk = 0; kk < KDIM; kk += 32) {
        __syncthreads();
        gload_lds16(Ab + kk, AsD0);
        gload_lds16(Ab + kk + 16 * KDIM, AsD1);
        gload_lds16(Bb + kk, BsD0);
        gload_lds16(Bb + kk + 16 * KDIM, BsD1);
        __syncthreads();
        bf16x8 af[4], bfr[4];
#pragma unroll
        for (int i = 0; i < 4; ++i) {
            af[i]  = *(const bf16x8*)(As + (rbA + i * 16) * 32 + kh);
            bfr[i] = *(const bf16x8*)(Bs + (rbB + i * 16) * 32 + kh);
        }
#pragma unroll
        for (int i = 0; i < 4; ++i)
#pragma unroll
            for (int j = 0; j < 4; ++j)
                acc[i][j] = __builtin_amdgcn_mfma_f32_16x16x32_bf16(af[i], bfr[j], acc[i][j], 0, 0, 0);
    }

#pragma unroll
    for (int i = 0; i < 4; ++i) {
        int mg = tm + wr * 64 + i * 16 + (lane >> 4) * 4;
#pragma unroll
        for (int j = 0; j < 4; ++j) {
            int o = tn + wc * 64 + j * 16 + (lane & 15);
#pragma unroll
            for (int r = 0; r < 4; ++r)
                out[(size_t)(mg + r) * DIN + o] = acc[i][j][r];
        }
    }
}

// ---------------------------------------------------------------- launch
extern "C" void kernel_launch(void* const* d_in, const int* in_sizes, int n_in,
                              void* d_out, int out_size, void* d_ws, size_t ws_size,
                              hipStream_t stream) {
    const float* x      = (const float*)d_in[0];
    const float* gamma  = (const float*)d_in[1];
    const float* w_qkv  = (const float*)d_in[2];
    const float* temp   = (const float*)d_in[3];
    const float* w_out  = (const float*)d_in[4];
    float* out = (float*)d_out;

    char* ws = (char*)d_ws;
    // workspace layout (~152 MB)
    bf16*  qkv    = (bf16*)ws;                       // 3*4096*4096*2 = 100663296 (v region transposed)
    bf16*  xn     = (bf16*)(ws + 100663296);         // 16384*1024*2  =  33554432
    bf16*  wq_bf  = (bf16*)(ws + 134217728);         //  3072*1024*2  =   6291456
    bf16*  wo_bf  = (bf16*)(ws + 140509184);         //  1024*1024*2  =   2097152
    float* ss     = (float*)(ws + 142606336);        //  8192*4       =     32768
    float* part   = (float*)(ws + 142639104);        //  64*8*4096*4  =   8388608
    bf16*  attnw  = (bf16*)(ws + 151027712);         //  64*4096*2    =    524288

    k_rmsnorm<<<MTOT, 256, 0, stream>>>(x, gamma, xn);
    k_cast_bf16<<<(NQO * KDIM / 4 + 255) / 256, 256, 0, stream>>>(w_qkv, wq_bf, NQO * KDIM / 4);
    k_cast_bf16<<<(DIN * KDIM / 4 + 255) / 256, 256, 0, stream>>>(w_out, wo_bf, DIN * KDIM / 4);
    k_zero<<<32, 256, 0, stream>>>(ss, 8192);
    k_gemm_qkv<<<dim3(NQO / 128, MTOT / 128), 256, 0, stream>>>(xn, wq_bf, qkv);
    k_sim<<<dim3(8, 64), 256, 0, stream>>>(qkv, part, ss);
    k_softfin<<<64, 256, 0, stream>>>(part, ss, temp, attnw);
    bf16* A2 = xn;  // xn is dead after GEMM1; reuse as attention-output buffer
    k_attnv<<<dim3(16, 64), 256, 0, stream>>>(qkv, attnw, A2);
    k_gemm_out<<<dim3(DIN / 128, MTOT / 128), 256, 0, stream>>>(A2, wo_bf, out);
}

// Round 10
// 328.597 us; speedup vs baseline: 1.3941x; 1.0660x over previous
//
#include <hip/hip_runtime.h>
#include <hip/hip_bf16.h>
#include <cstdint>
#include <cstddef>

// Problem constants
#define BB    4
#define NN    4096
#define DIM   1024
#define HEADS 16
#define DH    64
#define DIN   1024        // HEADS*DH
#define NQO   3072        // 3*DIN
#define MTOT  (BB*NN)     // 16384
#define KDIM  1024
#define EPS_F 1e-12f

using bf16 = __hip_bfloat16;
typedef __attribute__((ext_vector_type(8))) short bf16x8;
typedef __attribute__((ext_vector_type(4))) float f32x4;

// ---------------------------------------------------------------- helpers
__device__ __forceinline__ void gload_lds16(const void* g, void* l) {
    __builtin_amdgcn_global_load_lds(
        (const __attribute__((address_space(1))) void*)g,
        (__attribute__((address_space(3))) void*)l,
        16, 0, 0);
}

__device__ __forceinline__ ushort bf16_bits(float x) {
    union { bf16 h; ushort u; } c;
    c.h = __float2bfloat16(x);
    return c.u;
}

__device__ __forceinline__ float b2f(ushort u) {
    union { unsigned u32; float f; } c;
    c.u32 = ((unsigned)u) << 16;
    return c.f;
}

// ---------------------------------------------------------------- kernel 1: RMSNorm -> bf16
__global__ __launch_bounds__(256) void k_rmsnorm(const float* __restrict__ x,
                                                 const float* __restrict__ gamma,
                                                 bf16* __restrict__ xn) {
    int row = blockIdx.x;
    int t = threadIdx.x;                 // 256 threads, 4 f32 each = 1024
    const float4* xr = (const float4*)(x + (size_t)row * DIM);
    float4 v = xr[t];
    float ss = v.x * v.x + v.y * v.y + v.z * v.z + v.w * v.w;
#pragma unroll
    for (int off = 32; off; off >>= 1) ss += __shfl_down(ss, off, 64);
    __shared__ float red[4];
    int lane = t & 63, w = t >> 6;
    if (lane == 0) red[w] = ss;
    __syncthreads();
    float tot = red[0] + red[1] + red[2] + red[3];
    float scale = 32.0f / fmaxf(sqrtf(tot), EPS_F);   // sqrt(1024)=32
    float4 g = ((const float4*)gamma)[t];
    union { ushort4 u4; ushort us[4]; } o;
    o.us[0] = bf16_bits(v.x * scale * g.x);
    o.us[1] = bf16_bits(v.y * scale * g.y);
    o.us[2] = bf16_bits(v.z * scale * g.z);
    o.us[3] = bf16_bits(v.w * scale * g.w);
    ((ushort4*)(xn + (size_t)row * DIM))[t] = o.u4;
}

// ---------------------------------------------------------------- kernel 2: f32 -> bf16 cast
__global__ __launch_bounds__(256) void k_cast_bf16(const float* __restrict__ s,
                                                   bf16* __restrict__ d, int n4) {
    int i = blockIdx.x * blockDim.x + threadIdx.x;
    if (i >= n4) return;
    float4 v = ((const float4*)s)[i];
    union { ushort4 u4; ushort us[4]; } o;
    o.us[0] = bf16_bits(v.x); o.us[1] = bf16_bits(v.y);
    o.us[2] = bf16_bits(v.z); o.us[3] = bf16_bits(v.w);
    ((ushort4*)d)[i] = o.u4;
}

// ---------------------------------------------------------------- kernel 2b: zero ss buffer
__global__ __launch_bounds__(256) void k_zero(float* __restrict__ p, int n) {
    int i = blockIdx.x * 256 + threadIdx.x;
    if (i < n) p[i] = 0.0f;
}

// ---------------------------------------------------------------- 256x256x64 8-phase GEMM (T2+T3+T4+T5)
// C[m,o] = sum_k A[m,k]*W[o,k], A: Mx1024 bf16, W: Nx1024 bf16.
// 512 threads = 8 waves (2M x 4N); per-wave output 128x64 = acc[8][4].
// LDS 128 KiB: [buf][A(32KB) B(32KB)]; rows of 64 bf16 (128 B).
// XOR-swizzle byte ^= ((row&7)<<4): linear gload_lds dest + inverse-swizzled
// global source + swizzled ds_read (rule 21).
// MODE 0: qkv epilogue (q/k transposed scatter bf16, v -> vT[bh*4096+n][64])
// MODE 1: plain f32 row-major C.
// launch_bounds (512,1): 8-wave block forces 2 waves/SIMD -> 256-VGPR cap either way.
template<int MODE>
__global__ __launch_bounds__(512, 1) void k_gemm256(const bf16* __restrict__ A,
                                                    const bf16* __restrict__ W,
                                                    void* __restrict__ outp) {
    __shared__ short lds[65536];   // 128 KB
    char* ldsb = (char*)lds;
    const int t = threadIdx.x, lane = t & 63, wv = t >> 6;
    const int wm = wv >> 2, wn = wv & 3;
    const int tm = blockIdx.y * 256;
    const int tn = blockIdx.x * 256;
    const int NT = KDIM / 64;      // 16 K-tiles

    // ---- staging: round r covers tile rows [r*64 + wv*8, +8), lane l -> row +(l>>3)
    const int rowst = wv * 8 + (lane >> 3);
    const int srcxor = (((lane & 7) ^ (lane >> 3)) << 4);   // bytes within 128-B row
    const bf16* Asrc = A + (size_t)(tm + rowst) * KDIM;
    const bf16* Wsrc = W + (size_t)(tn + rowst) * KDIM;

#define STAGE(bufo_, kt_) do {                                                   \
    int k0_ = (kt_) * 64;                                                        \
    _Pragma("unroll")                                                            \
    for (int r_ = 0; r_ < 4; ++r_)                                               \
        gload_lds16((const char*)(Asrc + (size_t)r_ * 64 * KDIM + k0_) + srcxor, \
                    ldsb + (bufo_) + r_ * 8192 + wv * 1024);                     \
    _Pragma("unroll")                                                            \
    for (int r_ = 0; r_ < 4; ++r_)                                               \
        gload_lds16((const char*)(Wsrc + (size_t)r_ * 64 * KDIM + k0_) + srcxor, \
                    ldsb + (bufo_) + 32768 + r_ * 8192 + wv * 1024);             \
} while (0)

    // ---- ds_read offsets (bytes, excluding buf and mf/nf*2048)
    const int rxor = (lane & 7) << 4;
    int aoff[2], boff[2];
#pragma unroll
    for (int ks = 0; ks < 2; ++ks) {
        int cb = (ks * 64 + ((lane >> 4) << 4)) ^ rxor;
        aoff[ks] = (wm * 128 + (lane & 15)) * 128 + cb;
        boff[ks] = 32768 + (wn * 64 + (lane & 15)) * 128 + cb;
    }

    f32x4 acc[8][4] = {};
    bf16x8 af[8][2], bfr[4][2];

    STAGE(0, 0);
    asm volatile("s_waitcnt vmcnt(0)" ::: "memory");
    __syncthreads();

    for (int kt = 0; kt < NT; ++kt) {
        const int bufo = (kt & 1) << 16;
        // ---------------- phase 0: A mf0-3 + B nf0-1 reads, stage next tile
#pragma unroll
        for (int mf = 0; mf < 4; ++mf)
#pragma unroll
            for (int ks = 0; ks < 2; ++ks)
                af[mf][ks] = *(const bf16x8*)(ldsb + bufo + aoff[ks] + mf * 2048);
#pragma unroll
        for (int nf = 0; nf < 2; ++nf)
#pragma unroll
            for (int ks = 0; ks < 2; ++ks)
                bfr[nf][ks] = *(const bf16x8*)(ldsb + bufo + boff[ks] + nf * 2048);
        if (kt + 1 < NT) STAGE(bufo ^ 65536, kt + 1);
        __builtin_amdgcn_s_barrier();
        __builtin_amdgcn_s_setprio(1);
#pragma unroll
        for (int ks = 0; ks < 2; ++ks)
#pragma unroll
            for (int mf = 0; mf < 4; ++mf)
#pragma unroll
                for (int nf = 0; nf < 2; ++nf)
                    acc[mf][nf] = __builtin_amdgcn_mfma_f32_16x16x32_bf16(af[mf][ks], bfr[nf][ks], acc[mf][nf], 0, 0, 0);
        __builtin_amdgcn_s_setprio(0);
        __builtin_amdgcn_s_barrier();
        // ---------------- phase 1: A mf4-7 reads
#pragma unroll
        for (int mf = 4; mf < 8; ++mf)
#pragma unroll
            for (int ks = 0; ks < 2; ++ks)
                af[mf][ks] = *(const bf16x8*)(ldsb + bufo + aoff[ks] + mf * 2048);
        __builtin_amdgcn_s_barrier();
        __builtin_amdgcn_s_setprio(1);
#pragma unroll
        for (int ks = 0; ks < 2; ++ks)
#pragma unroll
            for (int mf = 4; mf < 8; ++mf)
#pragma unroll
                for (int nf = 0; nf < 2; ++nf)
                    acc[mf][nf] = __builtin_amdgcn_mfma_f32_16x16x32_bf16(af[mf][ks], bfr[nf][ks], acc[mf][nf], 0, 0, 0);
        __builtin_amdgcn_s_setprio(0);
        __builtin_amdgcn_s_barrier();
        // ---------------- phase 2: B nf2-3 reads
#pragma unroll
        for (int nf = 2; nf < 4; ++nf)
#pragma unroll
            for (int ks = 0; ks < 2; ++ks)
                bfr[nf][ks] = *(const bf16x8*)(ldsb + bufo + boff[ks] + nf * 2048);
        __builtin_amdgcn_s_barrier();
        __builtin_amdgcn_s_setprio(1);
#pragma unroll
        for (int ks = 0; ks < 2; ++ks)
#pragma unroll
            for (int mf = 0; mf < 4; ++mf)
#pragma unroll
                for (int nf = 2; nf < 4; ++nf)
                    acc[mf][nf] = __builtin_amdgcn_mfma_f32_16x16x32_bf16(af[mf][ks], bfr[nf][ks], acc[mf][nf], 0, 0, 0);
        __builtin_amdgcn_s_setprio(0);
        __builtin_amdgcn_s_barrier();
        // ---------------- phase 3: no reads; wait staging before swap
        __builtin_amdgcn_s_setprio(1);
#pragma unroll
        for (int ks = 0; ks < 2; ++ks)
#pragma unroll
            for (int mf = 4; mf < 8; ++mf)
#pragma unroll
                for (int nf = 2; nf < 4; ++nf)
                    acc[mf][nf] = __builtin_amdgcn_mfma_f32_16x16x32_bf16(af[mf][ks], bfr[nf][ks], acc[mf][nf], 0, 0, 0);
        __builtin_amdgcn_s_setprio(0);
        if (kt + 1 < NT) asm volatile("s_waitcnt vmcnt(0)" ::: "memory");
        __builtin_amdgcn_s_barrier();
    }
#undef STAGE

    // ---------------- epilogue. C/D frag: col=lane&15, row=(lane>>4)*4+reg
    if (MODE == 0) {
        bf16* qkv = (bf16*)outp;
        const int b = tm >> 12;   // 4096 rows per batch; 256-tile never straddles
        if (tn < 2048) {
#pragma unroll
            for (int mf = 0; mf < 8; ++mf) {
                int mg = tm + wm * 128 + mf * 16 + ((lane >> 4) << 2);
                int nseq = mg & (NN - 1);
#pragma unroll
                for (int nf = 0; nf < 4; ++nf) {
                    int o = tn + wn * 64 + nf * 16 + (lane & 15);
                    size_t row = (size_t)((o >> 10) * 4 + b) * 1024 + (o & 1023);
                    union { ushort4 u4; ushort us[4]; } pk;
#pragma unroll
                    for (int r = 0; r < 4; ++r) pk.us[r] = bf16_bits(acc[mf][nf][r]);
                    *(ushort4*)(qkv + row * NN + nseq) = pk.u4;
                }
            }
        } else {
            bf16* vT = qkv + (size_t)8192 * NN;   // v region, layout [bh*4096+n][64]
#pragma unroll
            for (int mf = 0; mf < 8; ++mf) {
                int mg = tm + wm * 128 + mf * 16 + ((lane >> 4) << 2);
                int nseq = mg & (NN - 1);
#pragma unroll
                for (int nf = 0; nf < 4; ++nf) {
                    int o = tn + wn * 64 + nf * 16 + (lane & 15);
                    int hd = o & 1023;
                    size_t base = ((size_t)(b * 16 + (hd >> 6)) * NN + nseq) * 64 + (hd & 63);
#pragma unroll
                    for (int r = 0; r < 4; ++r)
                        vT[base + (size_t)r * 64] = __float2bfloat16(acc[mf][nf][r]);
                }
            }
        }
    } else {
        float* out = (float*)outp;
#pragma unroll
        for (int mf = 0; mf < 8; ++mf) {
            int mg = tm + wm * 128 + mf * 16 + ((lane >> 4) << 2);
#pragma unroll
            for (int nf = 0; nf < 4; ++nf) {
                int o = tn + wn * 64 + nf * 16 + (lane & 15);
#pragma unroll
                for (int r = 0; r < 4; ++r)
                    out[(size_t)(mg + r) * DIN + o] = acc[mf][nf][r];
            }
        }
    }
}

// ---------------------------------------------------------------- kernel 5: sim partials via MFMA + fused row-norm ss
__global__ __launch_bounds__(256) void k_sim(const bf16* __restrict__ qkv,
                                             float* __restrict__ part,
                                             float* __restrict__ ss) {
    __shared__ short Ks[2][8192];   // 2 x 64 rows x 128 bf16 (16 KB each)
    const int chunk = blockIdx.x;   // 0..7, 512 n each
    const int bh = blockIdx.y;      // 0..63
    const int t = threadIdx.x, lane = t & 63, w = t >> 6;
    const bf16* qb = qkv + (size_t)(bh * 64) * NN;
    const bf16* kb = qkv + (size_t)(4096 + bh * 64) * NN;
    const int n0b = chunk * 512;

#define SIM_STAGE(buf, nt) do {                                              \
    int n0_ = n0b + (nt) * 128;                                              \
    _Pragma("unroll")                                                        \
    for (int cc = 0; cc < 4; ++cc) {                                         \
        int row_ = cc * 16 + (t >> 4);                                       \
        int colb_ = ((t & 15) << 4) ^ ((row_ & 7) << 4);                     \
        gload_lds16(kb + (size_t)row_ * NN + n0_ + (colb_ >> 1),             \
                    &Ks[buf][cc * 2048 + w * 512]);                          \
    }                                                                        \
} while (0)

    f32x4 acc[4] = {};
    float ssq = 0.f, ssk = 0.f;

    SIM_STAGE(0, 0);
    __syncthreads();
    for (int nt = 0; nt < 4; ++nt) {
        if (nt < 3) SIM_STAGE((nt + 1) & 1, nt + 1);
        {
            const int buf = nt & 1;
            const int n0 = n0b + nt * 128;
            bf16x8 af[4];
#pragma unroll
            for (int ks = 0; ks < 4; ++ks) {
                af[ks] = *(const bf16x8*)(qb + (size_t)(w * 16 + (lane & 15)) * NN +
                                          n0 + ks * 32 + ((lane >> 4) << 3));
#pragma unroll
                for (int i = 0; i < 8; ++i) { float f = b2f((ushort)af[ks][i]); ssq += f * f; }
            }
#pragma unroll
            for (int j = 0; j < 4; ++j) {
                int e = j * 16 + (lane & 15);
#pragma unroll
                for (int ks = 0; ks < 4; ++ks) {
                    bf16x8 bfr = *(const bf16x8*)((const char*)&Ks[buf][0] + e * 256 +
                                  ((ks * 64 + ((lane >> 4) << 4)) ^ ((e & 7) << 4)));
                    if (j == w) {
#pragma unroll
                        for (int i = 0; i < 8; ++i) { float f = b2f((ushort)bfr[i]); ssk += f * f; }
                    }
                    acc[j] = __builtin_amdgcn_mfma_f32_16x16x32_bf16(af[ks], bfr, acc[j], 0, 0, 0);
                }
            }
        }
        __syncthreads();
    }
#undef SIM_STAGE

    float vq = ssq; vq += __shfl_xor(vq, 16, 64); vq += __shfl_xor(vq, 32, 64);
    if (lane < 16) atomicAdd(&ss[bh * 64 + w * 16 + lane], vq);
    float vk = ssk; vk += __shfl_xor(vk, 16, 64); vk += __shfl_xor(vk, 32, 64);
    if (lane < 16) atomicAdd(&ss[4096 + bh * 64 + w * 16 + lane], vk);

    float* pb = part + (size_t)(bh * 8 + chunk) * 4096;
#pragma unroll
    for (int j = 0; j < 4; ++j) {
        int e = j * 16 + (lane & 15);
#pragma unroll
        for (int r = 0; r < 4; ++r) {
            int d = w * 16 + ((lane >> 4) << 2) + r;
            pb[d * 64 + e] = acc[j][r];
        }
    }
}

// ---------------------------------------------------------------- kernel 6: finalize + softmax -> bf16 attn[d][e]
__global__ __launch_bounds__(256) void k_softfin(const float* __restrict__ part,
                                                 const float* __restrict__ ss,
                                                 const float* __restrict__ temp,
                                                 bf16* __restrict__ attn) {
    int bh = blockIdx.x;
    int t = threadIdx.x, e = t & 63, w = t >> 6;
    float expT = __expf(temp[bh & (HEADS - 1)]);
    float ike = 8.0f * expT / fmaxf(sqrtf(ss[4096 + bh * 64 + e]), EPS_F);
    const float* pb = part + (size_t)bh * 8 * 4096;
#pragma unroll 2
    for (int dd = 0; dd < 16; ++dd) {
        int d = w * 16 + dd;
        float s = 0.f;
#pragma unroll
        for (int c = 0; c < 8; ++c) s += pb[c * 4096 + d * 64 + e];
        float invq = 1.0f / fmaxf(sqrtf(ss[bh * 64 + d]), EPS_F);
        float logit = s * ike * invq;
        float m = logit;
#pragma unroll
        for (int off = 32; off; off >>= 1) m = fmaxf(m, __shfl_xor(m, off, 64));
        float p = __expf(logit - m);
        float sum = p;
#pragma unroll
        for (int off = 32; off; off >>= 1) sum += __shfl_xor(sum, off, 64);
        attn[(size_t)bh * 4096 + d * 64 + e] = __float2bfloat16(p / sum);
    }
}

// ---------------------------------------------------------------- kernel 7: attn @ v via MFMA (no LDS, no barriers)
__global__ __launch_bounds__(256) void k_attnv(const bf16* __restrict__ qkv,
                                               const bf16* __restrict__ attn,
                                               bf16* __restrict__ A2) {
    const int nc = blockIdx.x;   // 0..15 (256 n each)
    const int bh = blockIdx.y;   // 0..63
    const int t = threadIdx.x, lane = t & 63, w = t >> 6;
    const bf16* vT = qkv + (size_t)8192 * NN + (size_t)bh * NN * 64;
    const bf16* ab = attn + (size_t)bh * 4096;
    const int nbase = nc * 256 + w * 64;

    bf16x8 bfr[4][2];
#pragma unroll
    for (int df = 0; df < 4; ++df)
#pragma unroll
        for (int ks = 0; ks < 2; ++ks)
            bfr[df][ks] = *(const bf16x8*)(ab + (df * 16 + (lane & 15)) * 64 +
                                           ks * 32 + ((lane >> 4) << 3));

    f32x4 acc[4][4] = {};
#pragma unroll
    for (int nf = 0; nf < 4; ++nf) {
#pragma unroll
        for (int ks = 0; ks < 2; ++ks) {
            bf16x8 af = *(const bf16x8*)(vT + (size_t)(nbase + nf * 16 + (lane & 15)) * 64 +
                                         ks * 32 + ((lane >> 4) << 3));
#pragma unroll
            for (int df = 0; df < 4; ++df)
                acc[nf][df] = __builtin_amdgcn_mfma_f32_16x16x32_bf16(af, bfr[df][ks], acc[nf][df], 0, 0, 0);
        }
    }
    const int b = bh >> 4, h = bh & 15;
#pragma unroll
    for (int nf = 0; nf < 4; ++nf)
#pragma unroll
        for (int df = 0; df < 4; ++df)
#pragma unroll
            for (int r = 0; r < 4; ++r) {
                int n = nbase + nf * 16 + ((lane >> 4) << 2) + r;
                int d = df * 16 + (lane & 15);
                A2[(size_t)(b * NN + n) * DIN + h * 64 + d] = __float2bfloat16(acc[nf][df][r]);
            }
}

// ---------------------------------------------------------------- launch
extern "C" void kernel_launch(void* const* d_in, const int* in_sizes, int n_in,
                              void* d_out, int out_size, void* d_ws, size_t ws_size,
                              hipStream_t stream) {
    const float* x      = (const float*)d_in[0];
    const float* gamma  = (const float*)d_in[1];
    const float* w_qkv  = (const float*)d_in[2];
    const float* temp   = (const float*)d_in[3];
    const float* w_out  = (const float*)d_in[4];
    float* out = (float*)d_out;

    char* ws = (char*)d_ws;
    // workspace layout (~152 MB)
    bf16*  qkv    = (bf16*)ws;                       // 3*4096*4096*2 = 100663296 (v region transposed)
    bf16*  xn     = (bf16*)(ws + 100663296);         // 16384*1024*2  =  33554432
    bf16*  wq_bf  = (bf16*)(ws + 134217728);         //  3072*1024*2  =   6291456
    bf16*  wo_bf  = (bf16*)(ws + 140509184);         //  1024*1024*2  =   2097152
    float* ss     = (float*)(ws + 142606336);        //  8192*4       =     32768
    float* part   = (float*)(ws + 142639104);        //  64*8*4096*4  =   8388608
    bf16*  attnw  = (bf16*)(ws + 151027712);         //  64*4096*2    =    524288

    k_rmsnorm<<<MTOT, 256, 0, stream>>>(x, gamma, xn);
    k_cast_bf16<<<(NQO * KDIM / 4 + 255) / 256, 256, 0, stream>>>(w_qkv, wq_bf, NQO * KDIM / 4);
    k_cast_bf16<<<(DIN * KDIM / 4 + 255) / 256, 256, 0, stream>>>(w_out, wo_bf, DIN * KDIM / 4);
    k_zero<<<32, 256, 0, stream>>>(ss, 8192);
    k_gemm256<0><<<dim3(NQO / 256, MTOT / 256), 512, 0, stream>>>(xn, wq_bf, (void*)qkv);
    k_sim<<<dim3(8, 64), 256, 0, stream>>>(qkv, part, ss);
    k_softfin<<<64, 256, 0, stream>>>(part, ss, temp, attnw);
    bf16* A2 = xn;  // xn is dead after GEMM1; reuse as attention-output buffer
    k_attnv<<<dim3(16, 64), 256, 0, stream>>>(qkv, attnw, A2);
    k_gemm256<1><<<dim3(DIN / 256, MTOT / 256), 512, 0, stream>>>(A2, wo_bf, (void*)out);
}